// Round 1
// baseline (1013.163 us; speedup 1.0000x reference)
//
#include <hip/hip_runtime.h>

// Problem: B=2, S=2048, E=1024, H=16, HD=64
constexpr int kB = 2;
constexpr int kS = 2048;
constexpr int kE = 1024;
constexpr int kF = 3 * kE;  // 3072

typedef __attribute__((ext_vector_type(8))) short short8;   // 8 bf16 (4 VGPRs) — MFMA A/B frag
typedef __attribute__((ext_vector_type(4))) float f32x4;    // MFMA C/D frag

__device__ __forceinline__ ushort f2bf_rne(float f) {
    uint u = __float_as_uint(f);
    return (ushort)((u + 0x7FFF + ((u >> 16) & 1)) >> 16);
}
__device__ __forceinline__ float bf2f(ushort u) {
    return __uint_as_float((uint)u << 16);
}

// ---------------------------------------------------------------------------
// fp32 -> bf16 cast (RNE), 4 elements/thread
// ---------------------------------------------------------------------------
__global__ __launch_bounds__(256) void k_cast(const float* __restrict__ in,
                                              ushort* __restrict__ out, int n4)
{
    int i = blockIdx.x * 256 + threadIdx.x;
    if (i < n4) {
        float4 v = ((const float4*)in)[i];
        ushort4 o;
        o.x = f2bf_rne(v.x); o.y = f2bf_rne(v.y);
        o.z = f2bf_rne(v.z); o.w = f2bf_rne(v.w);
        ((ushort4*)out)[i] = o;
    }
}

// ---------------------------------------------------------------------------
// Stage a 64x64 bf16 tile (row stride gstride elems) into LDS [64][72]
// (256-thread version, used by k_vt)
// ---------------------------------------------------------------------------
__device__ __forceinline__ void stage64(ushort* __restrict__ Ls,
                                        const ushort* __restrict__ g,
                                        int gstride, int tid)
{
    int r = tid >> 3;
    int c = (tid & 7) << 3;
    *(uint4*)(Ls + r * 72 + c)        = *(const uint4*)(g + (size_t)r * gstride + c);
    *(uint4*)(Ls + (r + 32) * 72 + c) = *(const uint4*)(g + (size_t)(r + 32) * gstride + c);
}

// ---------------------------------------------------------------------------
// Generic bf16 MFMA GEMM-NT: C[M,N] = A[M,K] . B[N,K]^T + bias
// 128x128 tile, 4 waves (2x2), each wave 64x64 = 4x4 grid of 16x16x32 MFMAs.
// Cb!=null -> bf16 out (cols < qcols additionally scaled by 0.125 AFTER bias).
// ---------------------------------------------------------------------------
__global__ __launch_bounds__(256) void k_gemm(const ushort* __restrict__ A,
                                              const ushort* __restrict__ Bw,
                                              const float* __restrict__ bias,
                                              ushort* __restrict__ Cb,
                                              float* __restrict__ Cf,
                                              int K, int ldc, int qcols)
{
    __shared__ ushort As[128 * 40];  // rows m, 32 k (pad->40): 80B rows, 16B-mult
    __shared__ ushort Bs[128 * 40];
    const int tid = threadIdx.x;
    const int wave = tid >> 6, lane = tid & 63;
    const int quad = lane >> 4, c16 = lane & 15;
    const int wm = (wave >> 1) * 64, wn = (wave & 1) * 64;
    const int row0 = blockIdx.y * 128, col0 = blockIdx.x * 128;

    f32x4 acc[4][4];
#pragma unroll
    for (int i = 0; i < 4; ++i)
#pragma unroll
        for (int j = 0; j < 4; ++j) acc[i][j] = (f32x4){0.f, 0.f, 0.f, 0.f};

    const int sr = tid >> 2;
    const int sq = (tid & 3) << 3;

    for (int k0 = 0; k0 < K; k0 += 32) {
        __syncthreads();
        *(uint4*)(As + sr * 40 + sq)        = *(const uint4*)(A + (size_t)(row0 + sr) * K + k0 + sq);
        *(uint4*)(As + (sr + 64) * 40 + sq) = *(const uint4*)(A + (size_t)(row0 + sr + 64) * K + k0 + sq);
        *(uint4*)(Bs + sr * 40 + sq)        = *(const uint4*)(Bw + (size_t)(col0 + sr) * K + k0 + sq);
        *(uint4*)(Bs + (sr + 64) * 40 + sq) = *(const uint4*)(Bw + (size_t)(col0 + sr + 64) * K + k0 + sq);
        __syncthreads();

        short8 af[4], bf[4];
#pragma unroll
        for (int mt = 0; mt < 4; ++mt)
            af[mt] = *(const short8*)(As + (size_t)(wm + mt * 16 + c16) * 40 + quad * 8);
#pragma unroll
        for (int nt = 0; nt < 4; ++nt)
            bf[nt] = *(const short8*)(Bs + (size_t)(wn + nt * 16 + c16) * 40 + quad * 8);
#pragma unroll
        for (int mt = 0; mt < 4; ++mt)
#pragma unroll
            for (int nt = 0; nt < 4; ++nt)
                acc[mt][nt] = __builtin_amdgcn_mfma_f32_16x16x32_bf16(af[mt], bf[nt], acc[mt][nt], 0, 0, 0);
    }

#pragma unroll
    for (int nt = 0; nt < 4; ++nt) {
        const int colg = col0 + wn + nt * 16 + c16;
        const float bv = bias[colg];
        const float sc = (colg < qcols) ? 0.125f : 1.0f;
#pragma unroll
        for (int mt = 0; mt < 4; ++mt)
#pragma unroll
            for (int r = 0; r < 4; ++r) {
                const int rowg = row0 + wm + mt * 16 + quad * 4 + r;
                float v = acc[mt][nt][r] + bv;
                if (Cb) Cb[(size_t)rowg * ldc + colg] = f2bf_rne(v * sc);
                else    Cf[(size_t)rowg * ldc + colg] = v;
            }
    }
}

// ---------------------------------------------------------------------------
// Transpose V slice of qkv_bf16 into vT[b][h*64+d][s]
// ---------------------------------------------------------------------------
__global__ __launch_bounds__(256) void k_vt(const ushort* __restrict__ qkvb,
                                            ushort* __restrict__ vT)
{
    const int b = blockIdx.z, si = blockIdx.y, di = blockIdx.x;
    __shared__ ushort Ls[64 * 72];
    const int tid = threadIdx.x;
    stage64(Ls, qkvb + ((size_t)(b * kS + si * 64)) * kF + 2 * kE + di * 64, kF, tid);
    __syncthreads();
    const int dd = tid >> 3;
    const int s8 = (tid & 7) << 3;
#pragma unroll
    for (int it = 0; it < 2; ++it) {
        const int d = dd + it * 32;
        uint o[4];
#pragma unroll
        for (int i = 0; i < 4; ++i) {
            uint lo = Ls[(s8 + 2 * i) * 72 + d];
            uint hi = Ls[(s8 + 2 * i + 1) * 72 + d];
            o[i] = lo | (hi << 16);
        }
        *(uint4*)(vT + ((size_t)(b * kE + di * 64 + d)) * kS + si * 64 + s8) = *(uint4*)o;
    }
}

// ---------------------------------------------------------------------------
// Fused attention, single-QK^T structure with LDS score cache.
// Block: 512 threads (8 waves), 32 q-rows of one (b,h).
// LDS: Scache[32][SP] bf16 (scores then e), K/V dbuf [64][72]x2, stat scratch.
// Phase 1: S = Q.K^T once -> Scache as bf16 (offset by -3 for precision),
//          row max tracked in REGISTERS (no per-tile shuffles).
// Phase 2: one sweep: e = exp(t-m), row sum, write e back in place.
// Phase 3: PV from e-cache (A-frags straight from LDS) + fused normalized
//          wts store; o scaled by 1/l at the end.
// ---------------------------------------------------------------------------
constexpr int SP = 2056;                 // Scache row stride (shorts): 4112 B = 1028 dw ≡ 4 (mod 32) -> uniform banks
constexpr int SC_SH = 32 * SP;           // score cache shorts
constexpr int KB_SH = 64 * 72;           // one K/V tile buffer
constexpr int ATTN_LDS_BYTES = (SC_SH + 2 * KB_SH) * 2 + (32 * 4 + 32) * 4;  // 150,656 B

__global__ __launch_bounds__(512) void k_attn(const ushort* __restrict__ qkvb,
                                              const ushort* __restrict__ vT,
                                              float* __restrict__ wts,
                                              ushort* __restrict__ aob)
{
    extern __shared__ ushort smem[];
    ushort* Sc  = smem;                        // [32][SP]
    ushort* Kb0 = Sc + SC_SH;                  // [64][72]
    ushort* Kb1 = Kb0 + KB_SH;                 // [64][72]
    float* maxscr = (float*)(Kb1 + KB_SH);     // [32][4]
    float* invls  = maxscr + 32 * 4;           // [32]

    const int tid  = threadIdx.x;
    const int wave = tid >> 6, lane = tid & 63;
    const int quad = lane >> 4, c16 = lane & 15;
    const int z = blockIdx.y;
    const int b = z >> 4, h = z & 15;
    const int Rq = blockIdx.x * 32;
    const int mb = (wave & 1) * 16;            // q sub-block (0 or 16)
    const int nb = (wave >> 1) * 16;           // k/d sub-block (0,16,32,48)

    const ushort* qg  = qkvb + ((size_t)(b * kS + Rq)) * kF + h * 64;   // q (pre-scaled)
    const ushort* kg  = qkvb + ((size_t)b * kS) * kF + kE + h * 64;     // k
    const ushort* vtg = vT + ((size_t)(b * kE + h * 64)) * kS;          // v^T rows d

    // staging coords: 512 threads cover one 64x64 bf16 tile, 16B each
    const int strow = tid >> 3, stcol = (tid & 7) << 3;

    // Q A-frags direct from global (no LDS round-trip)
    const short8 qa0 = *(const short8*)(qg + (size_t)(mb + c16) * kF + quad * 8);
    const short8 qa1 = *(const short8*)(qg + (size_t)(mb + c16) * kF + quad * 8 + 32);

    // ---- phase 1: scores -> Scache (bf16, t = s - 3), register max ----
    constexpr float Coff = 3.0f;
    float m4[4] = {-1e30f, -1e30f, -1e30f, -1e30f};

    *(uint4*)(Kb0 + strow * 72 + stcol) = *(const uint4*)(kg + (size_t)strow * kF + stcol);
    __syncthreads();

#pragma unroll 2
    for (int j = 0; j < 32; ++j) {
        const ushort* cur = (j & 1) ? Kb1 : Kb0;
        ushort* nxt       = (j & 1) ? Kb0 : Kb1;
        if (j + 1 < 32)
            *(uint4*)(nxt + strow * 72 + stcol) =
                *(const uint4*)(kg + (size_t)((j + 1) * 64 + strow) * kF + stcol);

        short8 b0 = *(const short8*)(cur + (size_t)(nb + c16) * 72 + quad * 8);
        short8 b1 = *(const short8*)(cur + (size_t)(nb + c16) * 72 + quad * 8 + 32);
        f32x4 a = (f32x4){0.f, 0.f, 0.f, 0.f};
        a = __builtin_amdgcn_mfma_f32_16x16x32_bf16(qa0, b0, a, 0, 0, 0);
        a = __builtin_amdgcn_mfma_f32_16x16x32_bf16(qa1, b1, a, 0, 0, 0);
#pragma unroll
        for (int r = 0; r < 4; ++r) {
            const float t = a[r] - Coff;
            m4[r] = fmaxf(m4[r], t);
            Sc[(size_t)(mb + quad * 4 + r) * SP + j * 64 + nb + c16] = f2bf_rne(t);
        }
        __syncthreads();
    }

    // final max reduce: over the 16 c16 lanes, then across the 4 n-block waves
#pragma unroll
    for (int r = 0; r < 4; ++r) {
        float t = m4[r];
        t = fmaxf(t, __shfl_xor(t, 1));
        t = fmaxf(t, __shfl_xor(t, 2));
        t = fmaxf(t, __shfl_xor(t, 4));
        t = fmaxf(t, __shfl_xor(t, 8));
        if (c16 == 0) maxscr[(mb + quad * 4 + r) * 4 + (wave >> 1)] = t;
    }
    __syncthreads();

    // ---- phase 2: e = exp(t - m), row sums, write e back in place ----
    const int prow = wave * 4 + (lane >> 4);   // 0..31
    const float mt = fmaxf(fmaxf(maxscr[prow * 4 + 0], maxscr[prow * 4 + 1]),
                           fmaxf(maxscr[prow * 4 + 2], maxscr[prow * 4 + 3]));
    float ls0 = 0.f, ls1 = 0.f;
    ushort* rbase = Sc + (size_t)prow * SP + c16 * 8;
#pragma unroll 4
    for (int it = 0; it < 16; ++it) {
        short8 sv = *(const short8*)(rbase + it * 128);
        short8 ev;
#pragma unroll
        for (int i = 0; i < 8; ++i) {
            const float e = __expf(bf2f((ushort)sv[i]) - mt);
            if (i & 1) ls1 += e; else ls0 += e;
            ev[i] = (short)f2bf_rne(e);
        }
        *(short8*)(rbase + it * 128) = ev;
    }
    float lsum = ls0 + ls1;
    lsum += __shfl_xor(lsum, 1);
    lsum += __shfl_xor(lsum, 2);
    lsum += __shfl_xor(lsum, 4);
    lsum += __shfl_xor(lsum, 8);
    if (c16 == 0) invls[prow] = 1.0f / lsum;
    __syncthreads();

    // ---- phase 3: O = E.V (MFMA from e-cache) + fused normalized wts ----
    const float invl_m = invls[mb + c16];      // for wts rows (A-frag row)
    f32x4 o = (f32x4){0.f, 0.f, 0.f, 0.f};

    *(uint4*)(Kb0 + strow * 72 + stcol) = *(const uint4*)(vtg + (size_t)strow * kS + stcol);
    __syncthreads();

#pragma unroll 2
    for (int j = 0; j < 32; ++j) {
        const ushort* cur = (j & 1) ? Kb1 : Kb0;
        ushort* nxt       = (j & 1) ? Kb0 : Kb1;
        if (j + 1 < 32)
            *(uint4*)(nxt + strow * 72 + stcol) =
                *(const uint4*)(vtg + (size_t)strow * kS + (j + 1) * 64 + stcol);

        const ushort* pr = Sc + (size_t)(mb + c16) * SP + j * 64 + quad * 8;
        short8 pa0 = *(const short8*)(pr);
        short8 pa1 = *(const short8*)(pr + 32);
        short8 v0 = *(const short8*)(cur + (size_t)(nb + c16) * 72 + quad * 8);
        short8 v1 = *(const short8*)(cur + (size_t)(nb + c16) * 72 + quad * 8 + 32);
        o = __builtin_amdgcn_mfma_f32_16x16x32_bf16(pa0, v0, o, 0, 0, 0);
        o = __builtin_amdgcn_mfma_f32_16x16x32_bf16(pa1, v1, o, 0, 0, 0);

        if (wave < 2) {  // waves 0,1 cover rows 0-15 / 16-31: write wts once
            float* wp = wts + ((size_t)z * kS + Rq + mb + c16) * kS + j * 64 + quad * 8;
            float4 w0, w1, w2, w3;
            w0.x = bf2f((ushort)pa0[0]) * invl_m; w0.y = bf2f((ushort)pa0[1]) * invl_m;
            w0.z = bf2f((ushort)pa0[2]) * invl_m; w0.w = bf2f((ushort)pa0[3]) * invl_m;
            w1.x = bf2f((ushort)pa0[4]) * invl_m; w1.y = bf2f((ushort)pa0[5]) * invl_m;
            w1.z = bf2f((ushort)pa0[6]) * invl_m; w1.w = bf2f((ushort)pa0[7]) * invl_m;
            w2.x = bf2f((ushort)pa1[0]) * invl_m; w2.y = bf2f((ushort)pa1[1]) * invl_m;
            w2.z = bf2f((ushort)pa1[2]) * invl_m; w2.w = bf2f((ushort)pa1[3]) * invl_m;
            w3.x = bf2f((ushort)pa1[4]) * invl_m; w3.y = bf2f((ushort)pa1[5]) * invl_m;
            w3.z = bf2f((ushort)pa1[6]) * invl_m; w3.w = bf2f((ushort)pa1[7]) * invl_m;
            *(float4*)(wp)      = w0;
            *(float4*)(wp + 4)  = w1;
            *(float4*)(wp + 32) = w2;
            *(float4*)(wp + 36) = w3;
        }
        __syncthreads();
    }

    // epilogue: o * (1/l) -> attn_out bf16
    const int orow = mb + quad * 4;
#pragma unroll
    for (int r = 0; r < 4; ++r) {
        const float iv = invls[orow + r];
        aob[((size_t)(b * kS + Rq + orow + r)) * kE + h * 64 + nb + c16] =
            f2bf_rne(o[r] * iv);
    }
}

// ---------------------------------------------------------------------------

extern "C" void kernel_launch(void* const* d_in, const int* in_sizes, int n_in,
                              void* d_out, int out_size, void* d_ws, size_t ws_size,
                              hipStream_t stream)
{
    const float* query = (const float*)d_in[0];
    const float* in_w  = (const float*)d_in[3];
    const float* in_b  = (const float*)d_in[4];
    const float* out_w = (const float*)d_in[5];
    const float* out_b = (const float*)d_in[6];

    float* out = (float*)d_out;                      // [2,2048,1024]
    float* wts = out + (size_t)kB * kS * kE;         // [2,16,2048,2048]

    constexpr size_t MB = 1u << 20;
    char* w = (char*)d_ws;
    ushort* qbf  = (ushort*)(w);             // query bf16      [4096,1024]  8 MB
    ushort* wbfi = (ushort*)(w + 8 * MB);    // in_proj_w bf16  [3072,1024]  6 MB
    ushort* wbfo = (ushort*)(w + 14 * MB);   // out_proj_w bf16 [1024,1024]  2 MB
    ushort* qkvb = (ushort*)(w + 16 * MB);   // qkv bf16        [4096,3072] 24 MB
    ushort* vT   = (ushort*)(w + 40 * MB);   // v^T bf16   [2,1024 d,2048 s] 8 MB
    ushort* aob  = (ushort*)(w + 48 * MB);   // attn_out bf16   [4096,1024]  8 MB

    dim3 blk(256);
    k_cast<<<dim3((4096 * 1024 / 4 + 255) / 256), blk, 0, stream>>>(query, qbf, 4096 * 1024 / 4);
    k_cast<<<dim3((3072 * 1024 / 4 + 255) / 256), blk, 0, stream>>>(in_w, wbfi, 3072 * 1024 / 4);
    k_cast<<<dim3((1024 * 1024 / 4 + 255) / 256), blk, 0, stream>>>(out_w, wbfo, 1024 * 1024 / 4);

    // qkv = query . in_proj_w^T + b  (q section scaled by 0.125), bf16 out
    k_gemm<<<dim3(kF / 128, 4096 / 128), blk, 0, stream>>>(qbf, wbfi, in_b, qkvb, nullptr, kE, kF, kE);

    k_vt<<<dim3(16, 32, 2), blk, 0, stream>>>(qkvb, vT);

    hipFuncSetAttribute(reinterpret_cast<const void*>(k_attn),
                        hipFuncAttributeMaxDynamicSharedMemorySize, ATTN_LDS_BYTES);
    k_attn<<<dim3(kS / 32, kB * 16), dim3(512), ATTN_LDS_BYTES, stream>>>(qkvb, vT, wts, aob);

    // out = attn_out . out_proj_w^T + b, fp32 out
    k_gemm<<<dim3(kE / 128, 4096 / 128), blk, 0, stream>>>(aob, wbfo, out_b, nullptr, out, kE, kE, 0);
}

// Round 2
// 873.902 us; speedup vs baseline: 1.1594x; 1.1594x over previous
//
#include <hip/hip_runtime.h>

// Problem: B=2, S=2048, E=1024, H=16, HD=64
constexpr int kB = 2;
constexpr int kS = 2048;
constexpr int kE = 1024;
constexpr int kF = 3 * kE;  // 3072

typedef __attribute__((ext_vector_type(8))) short short8;   // 8 bf16 (4 VGPRs) — MFMA A/B frag
typedef __attribute__((ext_vector_type(4))) float f32x4;    // MFMA C/D frag

__device__ __forceinline__ ushort f2bf_rne(float f) {
    uint u = __float_as_uint(f);
    return (ushort)((u + 0x7FFF + ((u >> 16) & 1)) >> 16);
}
__device__ __forceinline__ float bf2f(ushort u) {
    return __uint_as_float((uint)u << 16);
}

// ---------------------------------------------------------------------------
// fp32 -> bf16 cast (RNE), 4 elements/thread
// ---------------------------------------------------------------------------
__global__ __launch_bounds__(256) void k_cast(const float* __restrict__ in,
                                              ushort* __restrict__ out, int n4)
{
    int i = blockIdx.x * 256 + threadIdx.x;
    if (i < n4) {
        float4 v = ((const float4*)in)[i];
        ushort4 o;
        o.x = f2bf_rne(v.x); o.y = f2bf_rne(v.y);
        o.z = f2bf_rne(v.z); o.w = f2bf_rne(v.w);
        ((ushort4*)out)[i] = o;
    }
}

// ---------------------------------------------------------------------------
// Stage a 64x64 bf16 tile (row stride gstride elems) into LDS [64][72]
// (256-thread version, used by k_vt)
// ---------------------------------------------------------------------------
__device__ __forceinline__ void stage64(ushort* __restrict__ Ls,
                                        const ushort* __restrict__ g,
                                        int gstride, int tid)
{
    int r = tid >> 3;
    int c = (tid & 7) << 3;
    *(uint4*)(Ls + r * 72 + c)        = *(const uint4*)(g + (size_t)r * gstride + c);
    *(uint4*)(Ls + (r + 32) * 72 + c) = *(const uint4*)(g + (size_t)(r + 32) * gstride + c);
}

// ---------------------------------------------------------------------------
// Generic bf16 MFMA GEMM-NT: C[M,N] = A[M,K] . B[N,K]^T + bias
// 128x128 tile, 4 waves (2x2), each wave 64x64 = 4x4 grid of 16x16x32 MFMAs.
// Cb!=null -> bf16 out (cols < qcols additionally scaled by 0.125 AFTER bias).
// ---------------------------------------------------------------------------
__global__ __launch_bounds__(256) void k_gemm(const ushort* __restrict__ A,
                                              const ushort* __restrict__ Bw,
                                              const float* __restrict__ bias,
                                              ushort* __restrict__ Cb,
                                              float* __restrict__ Cf,
                                              int K, int ldc, int qcols)
{
    __shared__ ushort As[128 * 40];  // rows m, 32 k (pad->40): 80B rows, 16B-mult
    __shared__ ushort Bs[128 * 40];
    const int tid = threadIdx.x;
    const int wave = tid >> 6, lane = tid & 63;
    const int quad = lane >> 4, c16 = lane & 15;
    const int wm = (wave >> 1) * 64, wn = (wave & 1) * 64;
    const int row0 = blockIdx.y * 128, col0 = blockIdx.x * 128;

    f32x4 acc[4][4];
#pragma unroll
    for (int i = 0; i < 4; ++i)
#pragma unroll
        for (int j = 0; j < 4; ++j) acc[i][j] = (f32x4){0.f, 0.f, 0.f, 0.f};

    const int sr = tid >> 2;
    const int sq = (tid & 3) << 3;

    for (int k0 = 0; k0 < K; k0 += 32) {
        __syncthreads();
        *(uint4*)(As + sr * 40 + sq)        = *(const uint4*)(A + (size_t)(row0 + sr) * K + k0 + sq);
        *(uint4*)(As + (sr + 64) * 40 + sq) = *(const uint4*)(A + (size_t)(row0 + sr + 64) * K + k0 + sq);
        *(uint4*)(Bs + sr * 40 + sq)        = *(const uint4*)(Bw + (size_t)(col0 + sr) * K + k0 + sq);
        *(uint4*)(Bs + (sr + 64) * 40 + sq) = *(const uint4*)(Bw + (size_t)(col0 + sr + 64) * K + k0 + sq);
        __syncthreads();

        short8 af[4], bf[4];
#pragma unroll
        for (int mt = 0; mt < 4; ++mt)
            af[mt] = *(const short8*)(As + (size_t)(wm + mt * 16 + c16) * 40 + quad * 8);
#pragma unroll
        for (int nt = 0; nt < 4; ++nt)
            bf[nt] = *(const short8*)(Bs + (size_t)(wn + nt * 16 + c16) * 40 + quad * 8);
#pragma unroll
        for (int mt = 0; mt < 4; ++mt)
#pragma unroll
            for (int nt = 0; nt < 4; ++nt)
                acc[mt][nt] = __builtin_amdgcn_mfma_f32_16x16x32_bf16(af[mt], bf[nt], acc[mt][nt], 0, 0, 0);
    }

#pragma unroll
    for (int nt = 0; nt < 4; ++nt) {
        const int colg = col0 + wn + nt * 16 + c16;
        const float bv = bias[colg];
        const float sc = (colg < qcols) ? 0.125f : 1.0f;
#pragma unroll
        for (int mt = 0; mt < 4; ++mt)
#pragma unroll
            for (int r = 0; r < 4; ++r) {
                const int rowg = row0 + wm + mt * 16 + quad * 4 + r;
                float v = acc[mt][nt][r] + bv;
                if (Cb) Cb[(size_t)rowg * ldc + colg] = f2bf_rne(v * sc);
                else    Cf[(size_t)rowg * ldc + colg] = v;
            }
    }
}

// ---------------------------------------------------------------------------
// Transpose V slice of qkv_bf16 into vT[b][h*64+d][s]
// ---------------------------------------------------------------------------
__global__ __launch_bounds__(256) void k_vt(const ushort* __restrict__ qkvb,
                                            ushort* __restrict__ vT)
{
    const int b = blockIdx.z, si = blockIdx.y, di = blockIdx.x;
    __shared__ ushort Ls[64 * 72];
    const int tid = threadIdx.x;
    stage64(Ls, qkvb + ((size_t)(b * kS + si * 64)) * kF + 2 * kE + di * 64, kF, tid);
    __syncthreads();
    const int dd = tid >> 3;
    const int s8 = (tid & 7) << 3;
#pragma unroll
    for (int it = 0; it < 2; ++it) {
        const int d = dd + it * 32;
        uint o[4];
#pragma unroll
        for (int i = 0; i < 4; ++i) {
            uint lo = Ls[(s8 + 2 * i) * 72 + d];
            uint hi = Ls[(s8 + 2 * i + 1) * 72 + d];
            o[i] = lo | (hi << 16);
        }
        *(uint4*)(vT + ((size_t)(b * kE + di * 64 + d)) * kS + si * 64 + s8) = *(uint4*)o;
    }
}

// ---------------------------------------------------------------------------
// Fused attention v2: no K/V LDS staging (K/V panels are 256KB/head -> L2-fit;
// read MFMA B-frags directly from global). LDS holds ONLY a 16-row score
// cache. 3 barriers per block total; wts store is a barrier-free streaming
// phase by all 512 threads.
//   Block: 512 threads (8 waves), 16 q-rows of one (b,h). 2 blocks/CU.
//   Phase 1: QK^T once -> Sc bf16 (t = s - 3), per-wave 256-col stripe,
//            row max in registers. No barriers.
//   Phase 2: e = exp(t-m) sweep in place + row sums.
//   Phase 3: PV: A-frags from Sc, V-frags from global vT; waves split k in
//            halves; one LDS partial-sum exchange; aob written (o * 1/l).
//   Phase 4: wts = e * 1/l, streamed, no barriers.
// ---------------------------------------------------------------------------
constexpr int QR = 16;                   // q-rows per block
constexpr int SP = 2056;                 // Sc row stride (shorts): 4112 B = 1028 dw ≡ 4 (mod 32)
constexpr int SC_SH = QR * SP;
constexpr int ATTN_LDS_BYTES = SC_SH * 2 + (QR * 8) * 4 + QR * 4 + 8 * 256 * 4;  // 74,560 B

__global__ __launch_bounds__(512) void k_attn(const ushort* __restrict__ qkvb,
                                              const ushort* __restrict__ vT,
                                              float* __restrict__ wts,
                                              ushort* __restrict__ aob)
{
    extern __shared__ ushort smem[];
    ushort* Sc    = smem;                          // [QR][SP]
    float* maxscr = (float*)(Sc + SC_SH);          // [QR][8]
    float* invls  = maxscr + QR * 8;               // [QR]
    float* pvscr  = invls + QR;                    // [8][16][16]

    const int tid  = threadIdx.x;
    const int wave = tid >> 6, lane = tid & 63;
    const int quad = lane >> 4, c16 = lane & 15;
    const int z = blockIdx.y;
    const int b = z >> 4, h = z & 15;
    const int Rq = blockIdx.x * QR;

    const ushort* qg  = qkvb + ((size_t)(b * kS + Rq)) * kF + h * 64;   // q (pre-scaled)
    const ushort* kg  = qkvb + ((size_t)b * kS) * kF + kE + h * 64;     // k
    const ushort* vtg = vT + ((size_t)(b * kE + h * 64)) * kS;          // v^T rows d

    // Q A-frags direct from global (rows c16 of the 16-row q block)
    const short8 qa0 = *(const short8*)(qg + (size_t)c16 * kF + quad * 8);
    const short8 qa1 = *(const short8*)(qg + (size_t)c16 * kF + quad * 8 + 32);

    // ---- phase 1: scores -> Sc (bf16, t = s - 3), register max, no barriers ----
    constexpr float Coff = 3.0f;
    float m4[4] = {-1e30f, -1e30f, -1e30f, -1e30f};
    {
        const int colbase = wave * 256;   // this wave's 256-col stripe
#pragma unroll 4
        for (int t = 0; t < 16; ++t) {
            const ushort* kr = kg + (size_t)(colbase + t * 16 + c16) * kF;
            short8 b0 = *(const short8*)(kr + quad * 8);
            short8 b1 = *(const short8*)(kr + quad * 8 + 32);
            f32x4 a = (f32x4){0.f, 0.f, 0.f, 0.f};
            a = __builtin_amdgcn_mfma_f32_16x16x32_bf16(qa0, b0, a, 0, 0, 0);
            a = __builtin_amdgcn_mfma_f32_16x16x32_bf16(qa1, b1, a, 0, 0, 0);
#pragma unroll
            for (int r = 0; r < 4; ++r) {
                const float tv = a[r] - Coff;
                m4[r] = fmaxf(m4[r], tv);
                Sc[(size_t)(quad * 4 + r) * SP + colbase + t * 16 + c16] = f2bf_rne(tv);
            }
        }
    }
#pragma unroll
    for (int r = 0; r < 4; ++r) {
        float tv = m4[r];
        tv = fmaxf(tv, __shfl_xor(tv, 1));
        tv = fmaxf(tv, __shfl_xor(tv, 2));
        tv = fmaxf(tv, __shfl_xor(tv, 4));
        tv = fmaxf(tv, __shfl_xor(tv, 8));
        if (c16 == 0) maxscr[(quad * 4 + r) * 8 + wave] = tv;
    }
    __syncthreads();

    // ---- phase 2: e = exp(t - m) in place, row sums ----
    {
        const int prow = tid >> 5, l32 = tid & 31;   // 16 rows x 32 lanes
        float mr = maxscr[prow * 8];
#pragma unroll
        for (int i = 1; i < 8; ++i) mr = fmaxf(mr, maxscr[prow * 8 + i]);
        float ls = 0.f;
        ushort* rb = Sc + (size_t)prow * SP;
#pragma unroll
        for (int it = 0; it < 8; ++it) {
            const int col = it * 256 + l32 * 8;
            short8 sv = *(const short8*)(rb + col);
            short8 ev;
#pragma unroll
            for (int i = 0; i < 8; ++i) {
                const float e = __expf(bf2f((ushort)sv[i]) - mr);
                ls += e;
                ev[i] = (short)f2bf_rne(e);
            }
            *(short8*)(rb + col) = ev;
        }
        ls += __shfl_xor(ls, 1);
        ls += __shfl_xor(ls, 2);
        ls += __shfl_xor(ls, 4);
        ls += __shfl_xor(ls, 8);
        ls += __shfl_xor(ls, 16);
        if (l32 == 0) invls[prow] = 1.0f / ls;
    }
    __syncthreads();

    // ---- phase 3: O = E.V, A-frags from Sc, V-frags from global ----
    {
        const int nb = (wave & 3) * 16;   // d sub-block
        const int kh = wave >> 2;         // k half: [kh*1024, kh*1024+1024)
        f32x4 o = (f32x4){0.f, 0.f, 0.f, 0.f};
        const ushort* pb = Sc + (size_t)c16 * SP + kh * 1024 + quad * 8;
        const ushort* vb = vtg + (size_t)(nb + c16) * kS + kh * 1024 + quad * 8;
#pragma unroll 4
        for (int s = 0; s < 32; ++s) {
            short8 pa = *(const short8*)(pb + s * 32);
            short8 vf = *(const short8*)(vb + s * 32);
            o = __builtin_amdgcn_mfma_f32_16x16x32_bf16(pa, vf, o, 0, 0, 0);
        }
        float* ps = pvscr + wave * 256;
#pragma unroll
        for (int r = 0; r < 4; ++r) ps[(quad * 4 + r) * 16 + c16] = o[r];
    }
    __syncthreads();
    if (wave < 4) {
        const float* p0 = pvscr + wave * 256;
        const float* p1 = p0 + 4 * 256;
#pragma unroll
        for (int r = 0; r < 4; ++r) {
            const int row = quad * 4 + r;
            const float val = (p0[row * 16 + c16] + p1[row * 16 + c16]) * invls[row];
            aob[((size_t)(b * kS + Rq + row)) * kE + h * 64 + wave * 16 + c16] = f2bf_rne(val);
        }
    }

    // ---- phase 4: wts = e * 1/l, streaming, no barriers ----
    {
        const int row = tid >> 5, l32 = tid & 31;
        const float iv = invls[row];
        float* wp = wts + ((size_t)z * kS + Rq + row) * kS;
        const ushort* rb = Sc + (size_t)row * SP;
#pragma unroll
        for (int it = 0; it < 8; ++it) {
            const int col = it * 256 + l32 * 8;
            short8 ev = *(const short8*)(rb + col);
            float4 w0, w1;
            w0.x = bf2f((ushort)ev[0]) * iv; w0.y = bf2f((ushort)ev[1]) * iv;
            w0.z = bf2f((ushort)ev[2]) * iv; w0.w = bf2f((ushort)ev[3]) * iv;
            w1.x = bf2f((ushort)ev[4]) * iv; w1.y = bf2f((ushort)ev[5]) * iv;
            w1.z = bf2f((ushort)ev[6]) * iv; w1.w = bf2f((ushort)ev[7]) * iv;
            *(float4*)(wp + col)     = w0;
            *(float4*)(wp + col + 4) = w1;
        }
    }
}

// ---------------------------------------------------------------------------

extern "C" void kernel_launch(void* const* d_in, const int* in_sizes, int n_in,
                              void* d_out, int out_size, void* d_ws, size_t ws_size,
                              hipStream_t stream)
{
    const float* query = (const float*)d_in[0];
    const float* in_w  = (const float*)d_in[3];
    const float* in_b  = (const float*)d_in[4];
    const float* out_w = (const float*)d_in[5];
    const float* out_b = (const float*)d_in[6];

    float* out = (float*)d_out;                      // [2,2048,1024]
    float* wts = out + (size_t)kB * kS * kE;         // [2,16,2048,2048]

    constexpr size_t MB = 1u << 20;
    char* w = (char*)d_ws;
    ushort* qbf  = (ushort*)(w);             // query bf16      [4096,1024]  8 MB
    ushort* wbfi = (ushort*)(w + 8 * MB);    // in_proj_w bf16  [3072,1024]  6 MB
    ushort* wbfo = (ushort*)(w + 14 * MB);   // out_proj_w bf16 [1024,1024]  2 MB
    ushort* qkvb = (ushort*)(w + 16 * MB);   // qkv bf16        [4096,3072] 24 MB
    ushort* vT   = (ushort*)(w + 40 * MB);   // v^T bf16   [2,1024 d,2048 s] 8 MB
    ushort* aob  = (ushort*)(w + 48 * MB);   // attn_out bf16   [4096,1024]  8 MB

    dim3 blk(256);
    k_cast<<<dim3((4096 * 1024 / 4 + 255) / 256), blk, 0, stream>>>(query, qbf, 4096 * 1024 / 4);
    k_cast<<<dim3((3072 * 1024 / 4 + 255) / 256), blk, 0, stream>>>(in_w, wbfi, 3072 * 1024 / 4);
    k_cast<<<dim3((1024 * 1024 / 4 + 255) / 256), blk, 0, stream>>>(out_w, wbfo, 1024 * 1024 / 4);

    // qkv = query . in_proj_w^T + b  (q section scaled by 0.125), bf16 out
    k_gemm<<<dim3(kF / 128, 4096 / 128), blk, 0, stream>>>(qbf, wbfi, in_b, qkvb, nullptr, kE, kF, kE);

    k_vt<<<dim3(16, 32, 2), blk, 0, stream>>>(qkvb, vT);

    hipFuncSetAttribute(reinterpret_cast<const void*>(k_attn),
                        hipFuncAttributeMaxDynamicSharedMemorySize, ATTN_LDS_BYTES);
    k_attn<<<dim3(kS / QR, kB * 16), dim3(512), ATTN_LDS_BYTES, stream>>>(qkvb, vT, wts, aob);

    // out = attn_out . out_proj_w^T + b, fp32 out
    k_gemm<<<dim3(kE / 128, 4096 / 128), blk, 0, stream>>>(aob, wbfo, out_b, nullptr, out, kE, kE, 0);
}